// Round 17
// baseline (138.205 us; speedup 1.0000x reference)
//
#include <hip/hip_runtime.h>
#include <hip/hip_fp16.h>

static constexpr int N  = 100000;
static constexpr int E  = 1600000;
static constexpr int B  = 256;

static constexpr int BC     = 1024;                // kC block size
static constexpr int NBLKC  = 256;                 // kC grid (uniform, 1 block/CU)
static constexpr int CHUNKC = E / NBLKC;           // 6250 edges per kC block (exact)
static constexpr int PERC   = (CHUNKC + BC - 1) / BC;  // 7
static constexpr int NBUCK  = (N + 63) / 64;       // 1563 buckets of 64 nodes
static constexpr int SLAB   = 1536;                // slab cap (mean 1024, +16 sigma)
static constexpr int GCS    = 16;                  // gcur stride (64 B anti-conflict)

// ---- phase C: hist + wave-scan + slab reservation + run-copy write-out ------

__global__ __launch_bounds__(BC) void kC_scatter(
        const int* __restrict__ src, const int* __restrict__ dst,
        int* __restrict__ gcur, int* __restrict__ gslab) {
    __shared__ int lhist[NBUCK];
    __shared__ int lbase[NBUCK];
    __shared__ int gb[NBUCK];
    __shared__ int wsum[16];
    __shared__ int stage[CHUNKC];

    int t = threadIdx.x, blk = blockIdx.x;
    for (int i = t; i < NBUCK; i += BC) lhist[i] = 0;
    __syncthreads();

    int eb = blk * CHUNKC;
    int ds[PERC], ss[PERC];
#pragma unroll
    for (int k = 0; k < PERC; ++k) {
        int idx = k * BC + t;
        if (idx < CHUNKC) {
            ds[k] = dst[eb + idx];
            ss[k] = src[eb + idx];
            atomicAdd(&lhist[ds[k] >> 6], 1);
        }
    }
    __syncthreads();

    // blocked (2/thread) wave-shuffle exclusive scan of lhist[0..NBUCK)
    int lane = t & 63, wv = t >> 6;
    int i0 = 2 * t;
    int v0 = (i0 < NBUCK) ? lhist[i0] : 0;
    int v1 = (i0 + 1 < NBUCK) ? lhist[i0 + 1] : 0;
    int sum = v0 + v1;
    int inc = sum;
#pragma unroll
    for (int off = 1; off < 64; off <<= 1) {
        int u = __shfl_up(inc, off, 64);
        if (lane >= off) inc += u;
    }
    if (lane == 63) wsum[wv] = inc;
    __syncthreads();
    if (wv == 0) {
        int wval = (lane < 16) ? wsum[lane] : 0;
        int winc = wval;
#pragma unroll
        for (int off = 1; off < 16; off <<= 1) {
            int u = __shfl_up(winc, off, 64);
            if (lane >= off) winc += u;
        }
        if (lane < 16) wsum[lane] = winc - wval;   // exclusive wave base
    }
    __syncthreads();
    {
        int ex = wsum[wv] + inc - sum;
        if (i0 < NBUCK) lbase[i0] = ex;
        if (i0 + 1 < NBUCK) lbase[i0 + 1] = ex + v0;
    }
    __syncthreads();

    // reserve slab ranges; reset lhist as scatter cursor (strided: NBUCK > BC)
    for (int bb = t; bb < NBUCK; bb += BC) {
        int h = lhist[bb];
        if (h > 0) gb[bb] = bb * SLAB + atomicAdd(&gcur[bb * GCS], h);
        lhist[bb] = 0;
    }
    __syncthreads();

    // scatter into LDS stage, bucket-major; packed = (dst&63)<<17 | src
#pragma unroll
    for (int k = 0; k < PERC; ++k) {
        int idx = k * BC + t;
        if (idx < CHUNKC) {
            int d = ds[k], b = d >> 6;
            int r = atomicAdd(&lhist[b], 1);
            stage[lbase[b] + r] = ss[k] | ((d & 63) << 17);
        }
    }
    __syncthreads();

    // run-copy write-out: each bucket's contiguous run (strided over buckets)
    for (int bb = t; bb < NBUCK; bb += BC) {
        int len = lhist[bb];
        if (len > 0) {
            int s0 = lbase[bb];
            int g  = gb[bb];
            int cap = (bb + 1) * SLAB - g;
            if (cap < 0) cap = 0;
            if (len > cap) len = cap;
            for (int i = 0; i < len; ++i) gslab[g + i] = stage[s0 + i];
        }
    }
}

// ---- phase D1: per-bucket degree hist -> rofs + fp16 xpre -------------------

__global__ void kD1_deg(const int* __restrict__ gcur, const int* __restrict__ gslab,
                        int* __restrict__ rofs, const float4* __restrict__ x4,
                        __half* __restrict__ xpre) {
    __shared__ int c[64];
    int t = threadIdx.x, b = blockIdx.x;
    if (t < 64) c[t] = 0;
    __syncthreads();

    int ne = min(gcur[b * GCS], SLAB);
    int base = b * SLAB;                       // multiple of 4 -> int4 aligned
    int ne4 = ne & ~3;
    for (int k = 4 * t; k < ne4; k += 4 * B) {
        int4 p4 = *(const int4*)(gslab + base + k);
        atomicAdd(&c[p4.x >> 17], 1);
        atomicAdd(&c[p4.y >> 17], 1);
        atomicAdd(&c[p4.z >> 17], 1);
        atomicAdd(&c[p4.w >> 17], 1);
    }
    if (t < ne - ne4) atomicAdd(&c[gslab[base + ne4 + t] >> 17], 1);
    __syncthreads();

    // exclusive scan of c[0..64) via one wave scan (wave 0)
    int lane = t & 63;
    int val = (t < 64) ? c[t] : 0;
    int inc = val;
#pragma unroll
    for (int off = 1; off < 64; off <<= 1) {
        int u = __shfl_up(inc, off, 64);
        if (lane >= off) inc += u;
    }
    if (t < 64) rofs[b * 65 + t] = base + inc - val;
    if (t == 64) rofs[b * 65 + 64] = base + ne;

    // xpre = fp16(dis * x): 2 lanes/node, 8 halfs each (64 nodes -> 128 lanes)
    int n = b * 64 + (t >> 1), h = t & 1;
    if (t < 128 && n < N) {
        float d = rsqrtf((float)(c[t >> 1] + 1));
        float4 u0 = x4[(size_t)n * 4 + h * 2];
        float4 u1 = x4[(size_t)n * 4 + h * 2 + 1];
        ushort4 p0, p1;
        p0.x = __half_as_ushort(__float2half(u0.x * d));
        p0.y = __half_as_ushort(__float2half(u0.y * d));
        p0.z = __half_as_ushort(__float2half(u0.z * d));
        p0.w = __half_as_ushort(__float2half(u0.w * d));
        p1.x = __half_as_ushort(__float2half(u1.x * d));
        p1.y = __half_as_ushort(__float2half(u1.y * d));
        p1.z = __half_as_ushort(__float2half(u1.z * d));
        p1.w = __half_as_ushort(__float2half(u1.w * d));
        *(ushort4*)(xpre + (size_t)n * 16 + h * 8)     = p0;
        *(ushort4*)(xpre + (size_t)n * 16 + h * 8 + 4) = p1;
    }
}

// ---- phase D2: LDS node-sort + 4-lane/node register gather + fused dense ----

__global__ __launch_bounds__(B) void kD2_agg(
        const __half* __restrict__ xpre, int* __restrict__ gslab,
        const int* __restrict__ rofs, const float* __restrict__ W1,
        const float* __restrict__ b1, const float* __restrict__ W2,
        float2* __restrict__ hpre) {
    __shared__ int st1[SLAB];
    __shared__ int cur[64];
    __shared__ int lofs[65];
    __shared__ float acc[64 * 17];
    __shared__ float sW1[512], sb1[32], sW2[64];
    int t = threadIdx.x, b = blockIdx.x;
    for (int i = t; i < 512; i += B) sW1[i] = W1[i];
    if (t < 32) sb1[t] = b1[t];
    if (t < 64) sW2[t] = W2[t];
    if (t < 64) cur[t] = 0;
    int base = b * SLAB;
    if (t < 65) lofs[t] = rofs[b * 65 + t] - base;
    __syncthreads();

    int ne = lofs[64];
    // scatter into node-major LDS order (src-only payload)
    for (int k = t; k < ne; k += B) {
        int p = gslab[base + k];
        int lo = p >> 17;
        int r = atomicAdd(&cur[lo], 1);
        st1[lofs[lo] + r] = p & 0x1FFFF;
    }
    __syncthreads();
    // write sorted src list back (coalesced) for kF
    for (int k = t; k < ne; k += B) gslab[base + k] = st1[k];

    // register gather: 4 lanes/node = 2 channel-halves x 2 edge-halves
    {
        int nl = t >> 2, h = t & 1, eh = (t >> 1) & 1;
        int n = b * 64 + nl;
        float a0 = 0.f, a1 = 0.f, a2 = 0.f, a3 = 0.f;
        float a4 = 0.f, a5 = 0.f, a6 = 0.f, a7 = 0.f;
        if (n < N) {
            int rs = lofs[nl], re = lofs[nl + 1];
            if (eh == 0) {   // self-loop once
                int4 w = *(const int4*)(xpre + (size_t)n * 16 + h * 8);
                float2 q0 = __half22float2(*(__half2*)&w.x);
                float2 q1 = __half22float2(*(__half2*)&w.y);
                float2 q2 = __half22float2(*(__half2*)&w.z);
                float2 q3 = __half22float2(*(__half2*)&w.w);
                a0 = q0.x; a1 = q0.y; a2 = q1.x; a3 = q1.y;
                a4 = q2.x; a5 = q2.y; a6 = q3.x; a7 = q3.y;
            }
            auto add8 = [&](int4 w) {
                float2 q0 = __half22float2(*(__half2*)&w.x);
                float2 q1 = __half22float2(*(__half2*)&w.y);
                float2 q2 = __half22float2(*(__half2*)&w.z);
                float2 q3 = __half22float2(*(__half2*)&w.w);
                a0 += q0.x; a1 += q0.y; a2 += q1.x; a3 += q1.y;
                a4 += q2.x; a5 += q2.y; a6 += q3.x; a7 += q3.y;
            };
            int k = rs + eh;
            for (; k + 6 < re; k += 8) {
                int s0 = st1[k], s1 = st1[k + 2], s2 = st1[k + 4], s3 = st1[k + 6];
                int4 v0 = *(const int4*)(xpre + (size_t)s0 * 16 + h * 8);
                int4 v1 = *(const int4*)(xpre + (size_t)s1 * 16 + h * 8);
                int4 v2 = *(const int4*)(xpre + (size_t)s2 * 16 + h * 8);
                int4 v3 = *(const int4*)(xpre + (size_t)s3 * 16 + h * 8);
                add8(v0); add8(v1); add8(v2); add8(v3);
            }
            for (; k < re; k += 2)
                add8(*(const int4*)(xpre + (size_t)st1[k] * 16 + h * 8));
        }
        // combine edge-halves (partner lane = t ^ 2, same wave)
        a0 += __shfl_xor(a0, 2, 64); a1 += __shfl_xor(a1, 2, 64);
        a2 += __shfl_xor(a2, 2, 64); a3 += __shfl_xor(a3, 2, 64);
        a4 += __shfl_xor(a4, 2, 64); a5 += __shfl_xor(a5, 2, 64);
        a6 += __shfl_xor(a6, 2, 64); a7 += __shfl_xor(a7, 2, 64);
        if (n < N && eh == 0) {
            float* row = acc + nl * 17 + h * 8;
            row[0] = a0; row[1] = a1; row[2] = a2; row[3] = a3;
            row[4] = a4; row[5] = a5; row[6] = a6; row[7] = a7;
        }
    }
    __syncthreads();

    if (t < 64) {
        int n2 = b * 64 + t;
        if (n2 < N) {
            int deg = lofs[t + 1] - lofs[t];
            float d = rsqrtf((float)(deg + 1));
            const float* row = acc + t * 17;
            float xi[16];
#pragma unroll
            for (int k = 0; k < 16; ++k) xi[k] = row[k] * d;
            float o0 = 0.f, o1 = 0.f;
#pragma unroll
            for (int c = 0; c < 32; ++c) {
                float hh = sb1[c];
#pragma unroll
                for (int k = 0; k < 16; ++k) hh = fmaf(xi[k], sW1[k * 32 + c], hh);
                hh = fmaxf(hh, 0.f);
                o0 = fmaf(hh, sW2[c * 2 + 0], o0);
                o1 = fmaf(hh, sW2[c * 2 + 1], o1);
            }
            hpre[n2] = make_float2(d * o0, d * o1);
        }
    }
}

// ---- phase F: layer-2 node-major gather + bias ------------------------------

__global__ void kF_l2(const float2* __restrict__ hpre, const int* __restrict__ gslab,
                      const int* __restrict__ rofs, const float* __restrict__ b2,
                      float2* __restrict__ out) {
    int n = blockIdx.x * B + threadIdx.x;
    if (n >= N) return;
    int bb = n >> 6, lo = n & 63;
    int rs = rofs[bb * 65 + lo], re = rofs[bb * 65 + lo + 1];
    float2 self = hpre[n];
    float o0 = self.x, o1 = self.y;
    int k = rs;
    for (; k + 4 <= re; k += 4) {
        int s0 = gslab[k], s1 = gslab[k + 1], s2 = gslab[k + 2], s3 = gslab[k + 3];
        float2 v0 = hpre[s0];
        float2 v1 = hpre[s1];
        float2 v2 = hpre[s2];
        float2 v3 = hpre[s3];
        o0 += (v0.x + v1.x) + (v2.x + v3.x);
        o1 += (v0.y + v1.y) + (v2.y + v3.y);
    }
    for (; k < re; ++k) {
        float2 v = hpre[gslab[k]];
        o0 += v.x; o1 += v.y;
    }
    float d = rsqrtf((float)(re - rs + 1));
    out[n] = make_float2(fmaf(d, o0, b2[0]), fmaf(d, o1, b2[1]));
}

// ---- launcher ---------------------------------------------------------------

extern "C" void kernel_launch(void* const* d_in, const int* in_sizes, int n_in,
                              void* d_out, int out_size, void* d_ws, size_t ws_size,
                              hipStream_t stream) {
    const float* x  = (const float*)d_in[0];
    const int*   ei = (const int*)d_in[1];
    const float* W1 = (const float*)d_in[2];
    const float* b1 = (const float*)d_in[3];
    const float* W2 = (const float*)d_in[4];
    const float* b2 = (const float*)d_in[5];

    const int* src = ei;
    const int* dst = ei + E;

    // workspace layout (4-byte words; xpre offset 16 B aligned)
    int*    gslab = (int*)d_ws;                        // NBUCK*SLAB = 2,400,768
    int*    rofs  = gslab + (size_t)NBUCK * SLAB;      // 1563*65 = 101,595 -> pad 101,600
    int*    gcur  = rofs + 101600;                     // 1563*16 = 25,008
    float*  hpre  = (float*)(gcur + 25008);            // 2N
    __half* xpre  = (__half*)(hpre + 2 * (size_t)N);   // 16N halfs (3.2 MB)

    hipMemsetAsync(gcur, 0, NBUCK * GCS * sizeof(int), stream);
    kC_scatter<<<NBLKC, BC, 0, stream>>>(src, dst, gcur, gslab);
    kD1_deg<<<NBUCK, B, 0, stream>>>(gcur, gslab, rofs, (const float4*)x, xpre);
    kD2_agg<<<NBUCK, B, 0, stream>>>(xpre, gslab, rofs, W1, b1, W2, (float2*)hpre);
    kF_l2<<<(N + B - 1) / B, B, 0, stream>>>((const float2*)hpre, gslab, rofs, b2,
                                             (float2*)d_out);
}

// Round 18
// 126.020 us; speedup vs baseline: 1.0967x; 1.0967x over previous
//
#include <hip/hip_runtime.h>
#include <hip/hip_fp16.h>

static constexpr int N  = 100000;
static constexpr int E  = 1600000;
static constexpr int B  = 256;

static constexpr int BC     = 1024;                // kC block size
static constexpr int NBLKC  = 256;                 // kC grid (uniform, 1 block/CU)
static constexpr int CHUNKC = E / NBLKC;           // 6250 edges per kC block (exact)
static constexpr int PERC   = (CHUNKC + BC - 1) / BC;  // 7
static constexpr int NBUCK  = (N + 127) / 128;     // 782 buckets of 128 nodes
static constexpr int SLAB   = 3072;                // slab cap (mean 2048, +22 sigma)
static constexpr int GCS    = 16;                  // gcur stride (64 B anti-conflict)

// ---- phase C: hist + wave-scan + slab reservation + run-copy write-out ------

__global__ __launch_bounds__(BC) void kC_scatter(
        const int* __restrict__ src, const int* __restrict__ dst,
        int* __restrict__ gcur, int* __restrict__ gslab) {
    __shared__ int lhist[NBUCK];
    __shared__ int lbase[NBUCK];
    __shared__ int gb[NBUCK];
    __shared__ int wsum[16];
    __shared__ int stage[CHUNKC];

    int t = threadIdx.x, blk = blockIdx.x;
    for (int i = t; i < NBUCK; i += BC) lhist[i] = 0;
    __syncthreads();

    int eb = blk * CHUNKC;
    int ds[PERC], ss[PERC];
#pragma unroll
    for (int k = 0; k < PERC; ++k) {
        int idx = k * BC + t;
        if (idx < CHUNKC) {
            ds[k] = dst[eb + idx];
            ss[k] = src[eb + idx];
            atomicAdd(&lhist[ds[k] >> 7], 1);
        }
    }
    __syncthreads();

    // wave-shuffle exclusive scan of lhist[0..NBUCK) (one element per thread)
    int lane = t & 63, wv = t >> 6;
    int val = (t < NBUCK) ? lhist[t] : 0;
    int inc = val;
#pragma unroll
    for (int off = 1; off < 64; off <<= 1) {
        int u = __shfl_up(inc, off, 64);
        if (lane >= off) inc += u;
    }
    if (lane == 63) wsum[wv] = inc;
    __syncthreads();
    if (wv == 0) {
        int wval = (lane < 16) ? wsum[lane] : 0;
        int winc = wval;
#pragma unroll
        for (int off = 1; off < 16; off <<= 1) {
            int u = __shfl_up(winc, off, 64);
            if (lane >= off) winc += u;
        }
        if (lane < 16) wsum[lane] = winc - wval;   // exclusive wave base
    }
    __syncthreads();
    if (t < NBUCK) lbase[t] = wsum[wv] + inc - val;
    __syncthreads();

    // reserve slab ranges; reset lhist as scatter cursor
    if (t < NBUCK) {
        int h = lhist[t];
        if (h > 0) gb[t] = t * SLAB + atomicAdd(&gcur[t * GCS], h);
        lhist[t] = 0;
    }
    __syncthreads();

    // scatter into LDS stage, bucket-major; packed = (dst&127)<<17 | src
#pragma unroll
    for (int k = 0; k < PERC; ++k) {
        int idx = k * BC + t;
        if (idx < CHUNKC) {
            int d = ds[k], b = d >> 7;
            int r = atomicAdd(&lhist[b], 1);
            stage[lbase[b] + r] = ss[k] | ((d & 127) << 17);
        }
    }
    __syncthreads();

    // run-copy write-out: thread t owns bucket t's contiguous run (no search)
    if (t < NBUCK) {
        int len = lhist[t];
        if (len > 0) {
            int s0 = lbase[t];
            int g  = gb[t];
            int cap = (t + 1) * SLAB - g;  // slab overflow guard
            if (cap < 0) cap = 0;
            if (len > cap) len = cap;
            for (int i = 0; i < len; ++i) gslab[g + i] = stage[s0 + i];
        }
    }
}

// ---- phase D1: per-bucket degree hist -> rofs + fp16 xpre -------------------

__global__ void kD1_deg(const int* __restrict__ gcur, const int* __restrict__ gslab,
                        int* __restrict__ rofs, const float4* __restrict__ x4,
                        __half* __restrict__ xpre) {
    __shared__ int c[128];
    __shared__ int wq[2];
    int t = threadIdx.x, b = blockIdx.x;
    if (t < 128) c[t] = 0;
    __syncthreads();

    int ne = min(gcur[b * GCS], SLAB);
    int base = b * SLAB;                       // multiple of 4 -> int4 aligned
    int ne4 = ne & ~3;
    for (int k = 4 * t; k < ne4; k += 4 * B) {
        int4 p4 = *(const int4*)(gslab + base + k);
        atomicAdd(&c[p4.x >> 17], 1);
        atomicAdd(&c[p4.y >> 17], 1);
        atomicAdd(&c[p4.z >> 17], 1);
        atomicAdd(&c[p4.w >> 17], 1);
    }
    if (t < ne - ne4) atomicAdd(&c[gslab[base + ne4 + t] >> 17], 1);
    __syncthreads();

    // exclusive scan of c[0..128) via 2 wave scans
    int lane = t & 63, wv = t >> 6;
    int val = (t < 128) ? c[t] : 0;
    int inc = val;
#pragma unroll
    for (int off = 1; off < 64; off <<= 1) {
        int u = __shfl_up(inc, off, 64);
        if (lane >= off) inc += u;
    }
    if (t == 63) wq[0] = inc;
    __syncthreads();
    if (t < 128) rofs[b * 129 + t] = base + inc - val + ((wv == 1) ? wq[0] : 0);
    if (t == 128) rofs[b * 129 + 128] = base + ne;

    // xpre = fp16(dis * x): 2 lanes/node, 8 halfs each
    int n = b * 128 + (t >> 1), h = t & 1;
    if (n < N) {
        float d = rsqrtf((float)(c[t >> 1] + 1));
        float4 u0 = x4[(size_t)n * 4 + h * 2];
        float4 u1 = x4[(size_t)n * 4 + h * 2 + 1];
        ushort4 p0, p1;
        p0.x = __half_as_ushort(__float2half(u0.x * d));
        p0.y = __half_as_ushort(__float2half(u0.y * d));
        p0.z = __half_as_ushort(__float2half(u0.z * d));
        p0.w = __half_as_ushort(__float2half(u0.w * d));
        p1.x = __half_as_ushort(__float2half(u1.x * d));
        p1.y = __half_as_ushort(__float2half(u1.y * d));
        p1.z = __half_as_ushort(__float2half(u1.z * d));
        p1.w = __half_as_ushort(__float2half(u1.w * d));
        *(ushort4*)(xpre + (size_t)n * 16 + h * 8)     = p0;
        *(ushort4*)(xpre + (size_t)n * 16 + h * 8 + 4) = p1;
    }
}

// ---- phase D2: LDS node-sort + register gather + fused dense (no writeback) -

__global__ __launch_bounds__(B) void kD2_agg(
        const __half* __restrict__ xpre, const int* __restrict__ gslab,
        const int* __restrict__ rofs, const float* __restrict__ W1,
        const float* __restrict__ b1, const float* __restrict__ W2,
        float2* __restrict__ hpre) {
    __shared__ int st1[SLAB];
    __shared__ int cur[128];
    __shared__ int lofs[129];
    __shared__ float acc[128 * 17];
    __shared__ float sW1[512], sb1[32], sW2[64];
    int t = threadIdx.x, b = blockIdx.x;
    for (int i = t; i < 512; i += B) sW1[i] = W1[i];
    if (t < 32) sb1[t] = b1[t];
    if (t < 64) sW2[t] = W2[t];
    if (t < 128) cur[t] = 0;
    int base = b * SLAB;
    if (t < 129) lofs[t] = rofs[b * 129 + t] - base;
    __syncthreads();

    int ne = lofs[128];
    // scatter into node-major LDS order (src-only payload)
    for (int k = t; k < ne; k += B) {
        int p = gslab[base + k];
        int lo = p >> 17;
        int r = atomicAdd(&cur[lo], 1);
        st1[lofs[lo] + r] = p & 0x1FFFF;
    }
    __syncthreads();

    // register gather: lane-pair per node (nl in [0,128))
    int nl = t >> 1, h = t & 1;
    int n = b * 128 + nl;
    if (n < N) {
        int rs = lofs[nl], re = lofs[nl + 1];
        float a0, a1, a2, a3, a4, a5, a6, a7;
        {
            int4 w = *(const int4*)(xpre + (size_t)n * 16 + h * 8);
            float2 q0 = __half22float2(*(__half2*)&w.x);
            float2 q1 = __half22float2(*(__half2*)&w.y);
            float2 q2 = __half22float2(*(__half2*)&w.z);
            float2 q3 = __half22float2(*(__half2*)&w.w);
            a0 = q0.x; a1 = q0.y; a2 = q1.x; a3 = q1.y;
            a4 = q2.x; a5 = q2.y; a6 = q3.x; a7 = q3.y;
        }
        auto add8 = [&](int4 w) {
            float2 q0 = __half22float2(*(__half2*)&w.x);
            float2 q1 = __half22float2(*(__half2*)&w.y);
            float2 q2 = __half22float2(*(__half2*)&w.z);
            float2 q3 = __half22float2(*(__half2*)&w.w);
            a0 += q0.x; a1 += q0.y; a2 += q1.x; a3 += q1.y;
            a4 += q2.x; a5 += q2.y; a6 += q3.x; a7 += q3.y;
        };
        int k = rs;
        for (; k + 4 <= re; k += 4) {
            int s0 = st1[k], s1 = st1[k + 1], s2 = st1[k + 2], s3 = st1[k + 3];
            int4 v0 = *(const int4*)(xpre + (size_t)s0 * 16 + h * 8);
            int4 v1 = *(const int4*)(xpre + (size_t)s1 * 16 + h * 8);
            int4 v2 = *(const int4*)(xpre + (size_t)s2 * 16 + h * 8);
            int4 v3 = *(const int4*)(xpre + (size_t)s3 * 16 + h * 8);
            add8(v0); add8(v1); add8(v2); add8(v3);
        }
        for (; k < re; ++k)
            add8(*(const int4*)(xpre + (size_t)st1[k] * 16 + h * 8));
        float* row = acc + nl * 17 + h * 8;
        row[0] = a0; row[1] = a1; row[2] = a2; row[3] = a3;
        row[4] = a4; row[5] = a5; row[6] = a6; row[7] = a7;
    }
    __syncthreads();

    if (t < 128) {
        int n2 = b * 128 + t;
        if (n2 < N) {
            int deg = lofs[t + 1] - lofs[t];
            float d = rsqrtf((float)(deg + 1));
            const float* row = acc + t * 17;
            float xi[16];
#pragma unroll
            for (int k = 0; k < 16; ++k) xi[k] = row[k] * d;
            float o0 = 0.f, o1 = 0.f;
#pragma unroll
            for (int c = 0; c < 32; ++c) {
                float hh = sb1[c];
#pragma unroll
                for (int k = 0; k < 16; ++k) hh = fmaf(xi[k], sW1[k * 32 + c], hh);
                hh = fmaxf(hh, 0.f);
                o0 = fmaf(hh, sW2[c * 2 + 0], o0);
                o1 = fmaf(hh, sW2[c * 2 + 1], o1);
            }
            hpre[n2] = make_float2(d * o0, d * o1);
        }
    }
}

// ---- phase F: per-bucket LDS sort + layer-2 gather + bias -------------------

__global__ __launch_bounds__(B) void kF_l2(
        const float2* __restrict__ hpre, const int* __restrict__ gslab,
        const int* __restrict__ rofs, const float* __restrict__ b2,
        float2* __restrict__ out) {
    __shared__ int st1[SLAB];
    __shared__ int cur[128];
    __shared__ int lofs[129];
    int t = threadIdx.x, b = blockIdx.x;
    if (t < 128) cur[t] = 0;
    int base = b * SLAB;
    if (t < 129) lofs[t] = rofs[b * 129 + t] - base;
    __syncthreads();

    int ne = lofs[128];
    // node-major LDS sort (src-only payload)
    for (int k = t; k < ne; k += B) {
        int p = gslab[base + k];
        int lo = p >> 17;
        int r = atomicAdd(&cur[lo], 1);
        st1[lofs[lo] + r] = p & 0x1FFFF;
    }
    __syncthreads();

    // lane-pair per node, edge-split; st1 read from LDS
    int nl = t >> 1, eh = t & 1;
    int n = b * 128 + nl;
    float o0 = 0.f, o1 = 0.f;
    int rs = 0, re = 0;
    if (n < N) {
        rs = lofs[nl]; re = lofs[nl + 1];
        if (eh == 0) {
            float2 self = hpre[n];
            o0 = self.x; o1 = self.y;
        }
        int k = rs + eh;
        for (; k + 6 < re; k += 8) {
            int s0 = st1[k], s1 = st1[k + 2], s2 = st1[k + 4], s3 = st1[k + 6];
            float2 v0 = hpre[s0];
            float2 v1 = hpre[s1];
            float2 v2 = hpre[s2];
            float2 v3 = hpre[s3];
            o0 += (v0.x + v1.x) + (v2.x + v3.x);
            o1 += (v0.y + v1.y) + (v2.y + v3.y);
        }
        for (; k < re; k += 2) {
            float2 v = hpre[st1[k]];
            o0 += v.x; o1 += v.y;
        }
    }
    o0 += __shfl_xor(o0, 1, 64);
    o1 += __shfl_xor(o1, 1, 64);
    if (n < N && eh == 0) {
        float d = rsqrtf((float)(re - rs + 1));
        out[n] = make_float2(fmaf(d, o0, b2[0]), fmaf(d, o1, b2[1]));
    }
}

// ---- launcher ---------------------------------------------------------------

extern "C" void kernel_launch(void* const* d_in, const int* in_sizes, int n_in,
                              void* d_out, int out_size, void* d_ws, size_t ws_size,
                              hipStream_t stream) {
    const float* x  = (const float*)d_in[0];
    const int*   ei = (const int*)d_in[1];
    const float* W1 = (const float*)d_in[2];
    const float* b1 = (const float*)d_in[3];
    const float* W2 = (const float*)d_in[4];
    const float* b2 = (const float*)d_in[5];

    const int* src = ei;
    const int* dst = ei + E;

    // workspace layout (4-byte words; xpre offset stays 16 B aligned)
    int*    gslab = (int*)d_ws;                        // NBUCK*SLAB = 2,402,304
    int*    rofs  = gslab + (size_t)NBUCK * SLAB;      // 782*129 -> pad 100,880
    int*    gcur  = rofs + 100880;                     // 782*16 = 12,512
    float*  hpre  = (float*)(gcur + 12512);            // 2N
    __half* xpre  = (__half*)(hpre + 2 * (size_t)N);   // 16N halfs (3.2 MB)

    hipMemsetAsync(gcur, 0, NBUCK * GCS * sizeof(int), stream);
    kC_scatter<<<NBLKC, BC, 0, stream>>>(src, dst, gcur, gslab);
    kD1_deg<<<NBUCK, B, 0, stream>>>(gcur, gslab, rofs, (const float4*)x, xpre);
    kD2_agg<<<NBUCK, B, 0, stream>>>(xpre, gslab, rofs, W1, b1, W2, (float2*)hpre);
    kF_l2<<<NBUCK, B, 0, stream>>>((const float2*)hpre, gslab, rofs, b2,
                                   (float2*)d_out);
}